// Round 1
// baseline (100.864 us; speedup 1.0000x reference)
//
#include <hip/hip_runtime.h>
#include <hip/hip_bf16.h>
#include <cfloat>

// DGG_StraightThrough: the reference's softmax-over-singleton-axis makes
// log_p == 0 exactly, so y == temp broadcast over batch. Output is
// (y_hard - y) + y evaluated in fp32:
//   non-topk: (0 - t) + t == +0.0 exactly
//   topk:     (1 - t) + t  (~1.0 within 1 ulp)
// where topk = top-8 per row of temp (ties -> lowest index, like lax.top_k).

#define NROW 2048
#define KTOP 8
#define NBATCH 4

__global__ __launch_bounds__(256) void dgg_topk_row_kernel(
    const float* __restrict__ temp, float* __restrict__ out)
{
    __shared__ float vals[NROW];       // 8 KB row cache
    __shared__ float wv[4];
    __shared__ int   wi[4];
    __shared__ int   selIdx[KTOP];
    __shared__ float selVal[KTOP];

    const int n   = blockIdx.x;
    const int tid = threadIdx.x;
    const float* row = temp + (size_t)n * NROW;

    // ---- stage row into LDS (coalesced float4) ----
    const float4* row4 = (const float4*)row;
    for (int j = tid; j < NROW / 4; j += 256) {
        float4 v = row4[j];
        vals[j * 4 + 0] = v.x;
        vals[j * 4 + 1] = v.y;
        vals[j * 4 + 2] = v.z;
        vals[j * 4 + 3] = v.w;
    }
    __syncthreads();

    // ---- 8 successive block-wide argmax passes ----
    for (int p = 0; p < KTOP; ++p) {
        float bv = -FLT_MAX;
        int   bi = 0x7fffffff;
        // strided scan, increasing j: strictly-greater keeps lowest index among equals
        for (int j = tid; j < NROW; j += 256) {
            float v = vals[j];
            if (v > bv) { bv = v; bi = j; }
        }
        // wave64 shuffle reduce (lowest-index tie-break)
        for (int off = 32; off > 0; off >>= 1) {
            float ov = __shfl_down(bv, off);
            int   oi = __shfl_down(bi, off);
            if (ov > bv || (ov == bv && oi < bi)) { bv = ov; bi = oi; }
        }
        if ((tid & 63) == 0) { wv[tid >> 6] = bv; wi[tid >> 6] = bi; }
        __syncthreads();
        if (tid == 0) {
            float fv = wv[0]; int fi = wi[0];
            #pragma unroll
            for (int w = 1; w < 4; ++w) {
                if (wv[w] > fv || (wv[w] == fv && wi[w] < fi)) { fv = wv[w]; fi = wi[w]; }
            }
            selIdx[p] = fi;
            selVal[p] = fv;
            vals[fi] = -FLT_MAX;   // mask winner for next pass
        }
        __syncthreads();
    }

    // ---- stream zeros for this row, all 4 batches (coalesced float4) ----
    const float4 z = make_float4(0.f, 0.f, 0.f, 0.f);
    #pragma unroll
    for (int b = 0; b < NBATCH; ++b) {
        float4* o4 = (float4*)(out + ((size_t)b * NROW + n) * NROW);
        for (int j = tid; j < NROW / 4; j += 256) {
            o4[j] = z;
        }
    }
    __syncthreads();

    // ---- patch the 8 top-k entries per batch ----
    if (tid < KTOP) {
        const int   idx = selIdx[tid];
        const float t   = selVal[tid];
        const float val = (1.0f - t) + t;
        #pragma unroll
        for (int b = 0; b < NBATCH; ++b) {
            out[((size_t)b * NROW + n) * NROW + idx] = val;
        }
    }
}

extern "C" void kernel_launch(void* const* d_in, const int* in_sizes, int n_in,
                              void* d_out, int out_size, void* d_ws, size_t ws_size,
                              hipStream_t stream) {
    // inputs: 0:x  1:temp  2:W_proj  3:b_proj  4:W_dist  5:b_dist
    const float* temp = (const float*)d_in[1];
    float* out = (float*)d_out;
    dgg_topk_row_kernel<<<NROW, 256, 0, stream>>>(temp, out);
}